// Round 9
// baseline (142.443 us; speedup 1.0000x reference)
//
#include <hip/hip_runtime.h>

// out[t, j] = W[j, x[t]] + b[j]
//   x : [16384] int32, W : [1024, 50257] f32 row-major, b : [1024] f32
//   out: [16384, 1024] f32
//
// Established invariant (R2/R6/R8): one transaction per (token,j) = 16.8M
// divergent transactions = ~124us at ~4.5cyc/trans/CU. MLP depth (R6) and
// cache-path merging (R8) don't move it. Only transaction COUNT does.
// R9: bucket inversion in REGISTERS. One block per line-group (v>>4);
// thread tid holds W rows 4tid..4tid+3 x all 16 slots in float4 wv[4][4]
// (64 VGPR, compiler cannot sink: every serve iteration reads them).
// Staging: 16 dwordx4/thread, same-line loads adjacent (1 miss + 3 L1
// hits per line) -> each needed 64B line fetched EXACTLY ONCE: 3.2M
// transactions total (5.25x fewer). Serve: per token, uniform 16-way
// switch on u=v&15 (readfirstlane -> scalar branches, static reg indices)
// + fully coalesced float4 store. No LDS, no barriers.

#define VOCAB 50257
#define DIM   1024
#define NBUCK ((VOCAB + 15) >> 4)     // 3142 line-groups
#define NXCD  8

// ---------- sort pipeline (counting sort by v>>4) ----------

__global__ void zero_counts_kernel(int* __restrict__ counts, int n) {
    int i = blockIdx.x * blockDim.x + threadIdx.x;
    if (i < n) counts[i] = 0;
}

__global__ void hist_kernel(const int* __restrict__ x, int n, int* __restrict__ counts) {
    int i = blockIdx.x * blockDim.x + threadIdx.x;
    if (i < n) atomicAdd(&counts[x[i] >> 4], 1);
}

// single block, 256 threads: exclusive prefix sum over NBUCK counters
__global__ __launch_bounds__(256) void scan_kernel(const int* __restrict__ counts,
                                                   int* __restrict__ offs) {
    const int CHUNK = (NBUCK + 255) / 256;   // 13
    __shared__ int lds[256];
    const int tid = threadIdx.x;
    const int base = tid * CHUNK;
    int local[CHUNK];
    int s = 0;
#pragma unroll
    for (int k = 0; k < CHUNK; ++k) {
        int idx = base + k;
        int c = (idx < NBUCK) ? counts[idx] : 0;
        local[k] = s;
        s += c;
    }
    lds[tid] = s;
    __syncthreads();
    if (tid == 0) {
        int run = 0;
        for (int i = 0; i < 256; ++i) { int c = lds[i]; lds[i] = run; run += c; }
    }
    __syncthreads();
    const int boff = lds[tid];
#pragma unroll
    for (int k = 0; k < CHUNK; ++k) {
        int idx = base + k;
        if (idx < NBUCK) offs[idx] = boff + local[k];
    }
}

// offs consumed as running cursors (recomputed every call). Intra-bucket
// order is nondeterministic but out[t] depends only on t's own v ->
// deterministic OUTPUT. Packs (v << 16) | t : v < 65536, t < 65536.
// After this kernel, offs[g] == end offset of bucket g.
__global__ void scatter_kernel(const int* __restrict__ x, int n,
                               int* __restrict__ offs, int* __restrict__ order) {
    int i = blockIdx.x * blockDim.x + threadIdx.x;
    if (i < n) {
        int v = x[i];
        int pos = atomicAdd(&offs[v >> 4], 1);
        order[pos] = (v << 16) | i;
    }
}

// ---------- bucket gather, register-resident, barrier-free ----------
__global__ __launch_bounds__(256) void bucket_reg_gather(
    const float* __restrict__ W,
    const float* __restrict__ bias,
    const int* __restrict__ order,
    const int* __restrict__ ends,
    float* __restrict__ out)
{
    const int g = blockIdx.x;
    const int end = ends[g];
    const int start = (g == 0) ? 0 : ends[g - 1];
    if (end == start) return;            // empty bucket (~17 of 3142)

    const int vbase = g << 4;
    const int tid = threadIdx.x;
    const int j0 = tid * 4;

    // wv[jj][q] : rows j0+jj, vocab slots 4q..4q+3.  64 VGPRs of data.
    float4 wv[4][4];
    const bool full = (vbase + 16 <= VOCAB);   // block-uniform
    const float* row0 = W + (size_t)j0 * VOCAB + vbase;
    if (full) {
#pragma unroll
        for (int jj = 0; jj < 4; ++jj) {
            const float* r = row0 + (size_t)jj * VOCAB;
            // 4 contiguous dwordx4 from the SAME 64B line by the same lane:
            // 1 L2 transaction + 3 L1 hits.
            wv[jj][0] = *reinterpret_cast<const float4*>(r + 0);
            wv[jj][1] = *reinterpret_cast<const float4*>(r + 4);
            wv[jj][2] = *reinterpret_cast<const float4*>(r + 8);
            wv[jj][3] = *reinterpret_cast<const float4*>(r + 12);
        }
    } else {
        // last bucket only: per-element OOB guard
#pragma unroll
        for (int jj = 0; jj < 4; ++jj) {
            const float* r = row0 + (size_t)jj * VOCAB;
#pragma unroll
            for (int q = 0; q < 4; ++q) {
                float4 f;
                f.x = (vbase + 4 * q + 0 < VOCAB) ? r[4 * q + 0] : 0.f;
                f.y = (vbase + 4 * q + 1 < VOCAB) ? r[4 * q + 1] : 0.f;
                f.z = (vbase + 4 * q + 2 < VOCAB) ? r[4 * q + 2] : 0.f;
                f.w = (vbase + 4 * q + 3 < VOCAB) ? r[4 * q + 3] : 0.f;
                wv[jj][q] = f;
            }
        }
    }

    const float4 bb = *reinterpret_cast<const float4*>(bias + j0);

#define SERVE_CASE(U, Q, C)                                            \
    case U:                                                            \
        o.x = wv[0][Q].C; o.y = wv[1][Q].C;                            \
        o.z = wv[2][Q].C; o.w = wv[3][Q].C;                            \
        break;

    for (int i = start; i < end; ++i) {
        const int pk = __builtin_amdgcn_readfirstlane(order[i]); // uniform
        const int t = pk & 0xFFFF;
        const int u = (pk >> 16) & 15;
        float4 o;
        switch (u) {                      // uniform scalar branch, static regs
            SERVE_CASE(0, 0, x)  SERVE_CASE(1, 0, y)
            SERVE_CASE(2, 0, z)  SERVE_CASE(3, 0, w)
            SERVE_CASE(4, 1, x)  SERVE_CASE(5, 1, y)
            SERVE_CASE(6, 1, z)  SERVE_CASE(7, 1, w)
            SERVE_CASE(8, 2, x)  SERVE_CASE(9, 2, y)
            SERVE_CASE(10, 2, z) SERVE_CASE(11, 2, w)
            SERVE_CASE(12, 3, x) SERVE_CASE(13, 3, y)
            SERVE_CASE(14, 3, z) SERVE_CASE(15, 3, w)
            default: o.x = o.y = o.z = o.w = 0.f; break;
        }
        o.x += bb.x; o.y += bb.y; o.z += bb.z; o.w += bb.w;
        *reinterpret_cast<float4*>(out + (size_t)t * DIM + j0) = o; // coalesced
    }
#undef SERVE_CASE
}

// fallback (round-1 kernel) if workspace too small / n too large for packing
__global__ __launch_bounds__(256) void gather_direct_kernel(
    const int* __restrict__ x,
    const float* __restrict__ W,
    const float* __restrict__ bias,
    float* __restrict__ out)
{
    const int t = blockIdx.x;
    const int v = x[t];
    const int j0 = threadIdx.x * 4;
    float4 rr;
    rr.x = W[(size_t)(j0 + 0) * VOCAB + v];
    rr.y = W[(size_t)(j0 + 1) * VOCAB + v];
    rr.z = W[(size_t)(j0 + 2) * VOCAB + v];
    rr.w = W[(size_t)(j0 + 3) * VOCAB + v];
    const float4 bb = *reinterpret_cast<const float4*>(bias + j0);
    rr.x += bb.x; rr.y += bb.y; rr.z += bb.z; rr.w += bb.w;
    *reinterpret_cast<float4*>(out + (size_t)t * DIM + j0) = rr;
}

extern "C" void kernel_launch(void* const* d_in, const int* in_sizes, int n_in,
                              void* d_out, int out_size, void* d_ws, size_t ws_size,
                              hipStream_t stream) {
    const int*   x    = (const int*)d_in[0];
    const float* W    = (const float*)d_in[1];
    const float* bias = (const float*)d_in[2];
    float*       out  = (float*)d_out;

    const int n = in_sizes[0];           // 16384 tokens

    const size_t need = (size_t)(2 * NBUCK + n) * sizeof(int);
    if (ws_size < need || n > 65536) {   // packing uses 16 bits for token id
        gather_direct_kernel<<<n, 256, 0, stream>>>(x, W, bias, out);
        return;
    }

    int* counts = (int*)d_ws;            // [NBUCK]
    int* offs   = counts + NBUCK;        // [NBUCK] -> per-bucket end offsets
    int* order  = offs + NBUCK;          // [n] packed (v<<16 | t)

    const int tb = 256;
    zero_counts_kernel<<<(NBUCK + tb - 1) / tb, tb, 0, stream>>>(counts, NBUCK);
    hist_kernel<<<(n + tb - 1) / tb, tb, 0, stream>>>(x, n, counts);
    scan_kernel<<<1, tb, 0, stream>>>(counts, offs);
    scatter_kernel<<<(n + tb - 1) / tb, tb, 0, stream>>>(x, n, offs, order);

    bucket_reg_gather<<<NBUCK, 256, 0, stream>>>(W, bias, order, offs, out);
}

// Round 10
// 118.348 us; speedup vs baseline: 1.2036x; 1.2036x over previous
//
#include <hip/hip_runtime.h>

// out[t, j] = W[j, x[t]] + b[j]
//   x : [16384] int32, W : [1024, 50257] f32 row-major, b : [1024] f32
//   out: [16384, 1024] f32
//
// Invariant (R2/R6/R8): one transaction per (token,j) = 16.8M divergent
// transactions = ~124us. R9 proved the compiler demotes big per-thread
// register slabs to scratch (VGPR=40, FETCH +165MB scratch traffic).
// R10: bucket slab in LDS (cannot be demoted). One block per line-group
// (v>>4), 512 threads, full 64KB slab, ONE barrier. Stage: each thread
// reads 2 rows x 16 slots as 4x dwordx4 per row (full 64B line per lane,
// fetched exactly once) -> 3.2M line transactions total (5.25x fewer).
// LDS transposed slab[u][j], stride 1024: stage writes lane-consecutive j
// (conflict-free), serve reads wave-uniform u + contiguous float4
// (conflict-free). Serve: parallel over (token x j), 2 tokens/iter,
// coalesced 4KB row stores. 64KB LDS -> 2 blocks/CU: one block's serve
// overlaps the other's stage.

#define VOCAB 50257
#define DIM   1024
#define NBUCK ((VOCAB + 15) >> 4)     // 3142 line-groups
#define NXCD  8

// ---------- sort pipeline (counting sort by v>>4) ----------

__global__ void zero_counts_kernel(int* __restrict__ counts, int n) {
    int i = blockIdx.x * blockDim.x + threadIdx.x;
    if (i < n) counts[i] = 0;
}

__global__ void hist_kernel(const int* __restrict__ x, int n, int* __restrict__ counts) {
    int i = blockIdx.x * blockDim.x + threadIdx.x;
    if (i < n) atomicAdd(&counts[x[i] >> 4], 1);
}

// single block, 256 threads: exclusive prefix sum over NBUCK counters
__global__ __launch_bounds__(256) void scan_kernel(const int* __restrict__ counts,
                                                   int* __restrict__ offs) {
    const int CHUNK = (NBUCK + 255) / 256;   // 13
    __shared__ int lds[256];
    const int tid = threadIdx.x;
    const int base = tid * CHUNK;
    int local[CHUNK];
    int s = 0;
#pragma unroll
    for (int k = 0; k < CHUNK; ++k) {
        int idx = base + k;
        int c = (idx < NBUCK) ? counts[idx] : 0;
        local[k] = s;
        s += c;
    }
    lds[tid] = s;
    __syncthreads();
    if (tid == 0) {
        int run = 0;
        for (int i = 0; i < 256; ++i) { int c = lds[i]; lds[i] = run; run += c; }
    }
    __syncthreads();
    const int boff = lds[tid];
#pragma unroll
    for (int k = 0; k < CHUNK; ++k) {
        int idx = base + k;
        if (idx < NBUCK) offs[idx] = boff + local[k];
    }
}

// offs consumed as running cursors (recomputed every call). Intra-bucket
// order is nondeterministic but out[t] depends only on t's own v ->
// deterministic OUTPUT. Packs (v << 16) | t : v < 65536, t < 65536.
// After this kernel, offs[g] == end offset of bucket g.
__global__ void scatter_kernel(const int* __restrict__ x, int n,
                               int* __restrict__ offs, int* __restrict__ order) {
    int i = blockIdx.x * blockDim.x + threadIdx.x;
    if (i < n) {
        int v = x[i];
        int pos = atomicAdd(&offs[v >> 4], 1);
        order[pos] = (v << 16) | i;
    }
}

// ---------- bucket gather via LDS slab, one barrier ----------
__global__ __launch_bounds__(512) void bucket_lds_gather(
    const float* __restrict__ W,
    const float* __restrict__ bias,
    const int* __restrict__ order,
    const int* __restrict__ ends,
    float* __restrict__ out)
{
    extern __shared__ float slab[];      // [16][1024] = 65536 B, transposed

    const int g = blockIdx.x;
    const int end = ends[g];
    const int start = (g == 0) ? 0 : ends[g - 1];
    if (end == start) return;            // empty bucket; uniform -> safe

    const int vbase = g << 4;
    const int tid = threadIdx.x;

    // ---- stage: 2 rows/thread, 4x dwordx4 per row (1 full 64B line/lane) ----
    if (g != NBUCK - 1) {
#pragma unroll
        for (int rr = 0; rr < 2; ++rr) {
            const int j = tid + rr * 512;
            const float* r = W + (size_t)j * VOCAB + vbase;
            float4 a0 = *reinterpret_cast<const float4*>(r + 0);
            float4 a1 = *reinterpret_cast<const float4*>(r + 4);
            float4 a2 = *reinterpret_cast<const float4*>(r + 8);
            float4 a3 = *reinterpret_cast<const float4*>(r + 12);
            // transposed scalar writes: fixed u per instr, lane-consecutive j
            slab[ 0 * 1024 + j] = a0.x;  slab[ 1 * 1024 + j] = a0.y;
            slab[ 2 * 1024 + j] = a0.z;  slab[ 3 * 1024 + j] = a0.w;
            slab[ 4 * 1024 + j] = a1.x;  slab[ 5 * 1024 + j] = a1.y;
            slab[ 6 * 1024 + j] = a1.z;  slab[ 7 * 1024 + j] = a1.w;
            slab[ 8 * 1024 + j] = a2.x;  slab[ 9 * 1024 + j] = a2.y;
            slab[10 * 1024 + j] = a2.z;  slab[11 * 1024 + j] = a2.w;
            slab[12 * 1024 + j] = a3.x;  slab[13 * 1024 + j] = a3.y;
            slab[14 * 1024 + j] = a3.z;  slab[15 * 1024 + j] = a3.w;
        }
    } else {
        // last bucket: per-element OOB guard (1 block of 3142)
#pragma unroll
        for (int rr = 0; rr < 2; ++rr) {
            const int j = tid + rr * 512;
            const float* r = W + (size_t)j * VOCAB + vbase;
#pragma unroll
            for (int u = 0; u < 16; ++u)
                slab[u * 1024 + j] = (vbase + u < VOCAB) ? r[u] : 0.f;
        }
    }
    __syncthreads();

    // ---- serve: 2 tokens per iteration, parallel over j ----
    const int half = tid >> 8;           // 0 or 1 (wave-uniform)
    const int j4 = (tid & 255) * 4;
    const float4 bb = *reinterpret_cast<const float4*>(bias + j4);

    for (int i = start + half; i < end; i += 2) {
        const int pk = order[i];         // wave-uniform -> scalar load
        const int t = pk & 0xFFFF;
        const int u = (pk >> 16) & 15;
        const float4 wv = *reinterpret_cast<const float4*>(&slab[u * 1024 + j4]);
        float4 o;
        o.x = wv.x + bb.x; o.y = wv.y + bb.y;
        o.z = wv.z + bb.z; o.w = wv.w + bb.w;
        *reinterpret_cast<float4*>(out + (size_t)t * DIM + j4) = o; // 4KB coalesced
    }
}

// fallback (round-1 kernel) if workspace too small / n too large for packing
__global__ __launch_bounds__(256) void gather_direct_kernel(
    const int* __restrict__ x,
    const float* __restrict__ W,
    const float* __restrict__ bias,
    float* __restrict__ out)
{
    const int t = blockIdx.x;
    const int v = x[t];
    const int j0 = threadIdx.x * 4;
    float4 rr;
    rr.x = W[(size_t)(j0 + 0) * VOCAB + v];
    rr.y = W[(size_t)(j0 + 1) * VOCAB + v];
    rr.z = W[(size_t)(j0 + 2) * VOCAB + v];
    rr.w = W[(size_t)(j0 + 3) * VOCAB + v];
    const float4 bb = *reinterpret_cast<const float4*>(bias + j0);
    rr.x += bb.x; rr.y += bb.y; rr.z += bb.z; rr.w += bb.w;
    *reinterpret_cast<float4*>(out + (size_t)t * DIM + j0) = rr;
}

extern "C" void kernel_launch(void* const* d_in, const int* in_sizes, int n_in,
                              void* d_out, int out_size, void* d_ws, size_t ws_size,
                              hipStream_t stream) {
    const int*   x    = (const int*)d_in[0];
    const float* W    = (const float*)d_in[1];
    const float* bias = (const float*)d_in[2];
    float*       out  = (float*)d_out;

    const int n = in_sizes[0];           // 16384 tokens

    const size_t need = (size_t)(2 * NBUCK + n) * sizeof(int);
    if (ws_size < need || n > 65536) {   // packing uses 16 bits for token id
        gather_direct_kernel<<<n, 256, 0, stream>>>(x, W, bias, out);
        return;
    }

    int* counts = (int*)d_ws;            // [NBUCK]
    int* offs   = counts + NBUCK;        // [NBUCK] -> per-bucket end offsets
    int* order  = offs + NBUCK;          // [n] packed (v<<16 | t)

    const int tb = 256;
    zero_counts_kernel<<<(NBUCK + tb - 1) / tb, tb, 0, stream>>>(counts, NBUCK);
    hist_kernel<<<(n + tb - 1) / tb, tb, 0, stream>>>(x, n, counts);
    scan_kernel<<<1, tb, 0, stream>>>(counts, offs);
    scatter_kernel<<<(n + tb - 1) / tb, tb, 0, stream>>>(x, n, offs, order);

    bucket_lds_gather<<<NBUCK, 512, 65536, stream>>>(W, bias, order, offs, out);
}